// Round 3
// baseline (304.721 us; speedup 1.0000x reference)
//
#include <hip/hip_runtime.h>

// VectorQuantizer forward (VQ-VAE), MI355X/gfx950.
// Outputs (concatenated in d_out, read back as float32):
//   [0 .. N)            encoding indices (as float values)
//   [N .. N + N*D)      quantized rows (gathered codebook rows; STE value)
//   [N + N*D]           loss = 1.25 * mean((q - x)^2)
//
// Argmin strategy (round-3): replicate the reference's FLOAT32 semantics
// exactly. distances = fl32( fl32(s1 + s2_k) - 2*m_k ), where
//   s1  = sum(x^2)  (row-constant, ~64: its presence snaps distances to a
//                    7.6e-6 grid -> frequent exact ties -> first-index wins)
//   s2_k = sum(e_k^2)
//   m_k  = x . e_k  computed as a SERIAL ascending-j FMA chain (this is what
//          BLAS sgemm / Eigen gebp microkernels do: rank-1 updates into one
//          accumulator), so our chain is bit-identical to the CPU refs.
// s1/s2 use numpy's scalar pairwise summation scheme for n=64 (8 strided
// accumulators + binary-tree combine). Argmin ascending k, strict '<'
// (first index wins ties) == np.argmin.

#define NROWS (64 * 4096)            // 262144
#define DIMS 64
#define KCODES 512
#define BLOCK 512                    // threads per block (8 waves)
#define ROWS_PER_BLOCK 1024          // 2 rows per thread
#define GRID (NROWS / ROWS_PER_BLOCK)// 256 blocks == 1 per CU
#define CBS 17                       // float4 stride per code row (16 + 1 pad)

struct Lds {
  float4 cb[KCODES * CBS];   // padded codebook, 139264 B
  float  bf[KCODES];         // s2_k = sum(e_k^2), f32 pairwise
  int    kidx[ROWS_PER_BLOCK];
  double red[8];             // per-wave loss partials
};                           // ~145.5 KB <= 160 KiB

// numpy pairwise sum, n=64, scalar path: 8 strided accumulators, serial in i,
// then ((r0+r1)+(r2+r3)) + ((r4+r5)+(r6+r7)).
__device__ __forceinline__ float pairwise64_sq(const float4* v) {
  float a[64];
  #pragma unroll
  for (int c = 0; c < 16; ++c) {
    a[4 * c + 0] = v[c].x * v[c].x;
    a[4 * c + 1] = v[c].y * v[c].y;
    a[4 * c + 2] = v[c].z * v[c].z;
    a[4 * c + 3] = v[c].w * v[c].w;
  }
  float r0 = a[0], r1 = a[1], r2 = a[2], r3 = a[3];
  float r4 = a[4], r5 = a[5], r6 = a[6], r7 = a[7];
  #pragma unroll
  for (int i = 8; i < 64; i += 8) {
    r0 += a[i + 0]; r1 += a[i + 1]; r2 += a[i + 2]; r3 += a[i + 3];
    r4 += a[i + 4]; r5 += a[i + 5]; r6 += a[i + 6]; r7 += a[i + 7];
  }
  return ((r0 + r1) + (r2 + r3)) + ((r4 + r5) + (r6 + r7));
}

__global__ __launch_bounds__(BLOCK, 2) void vq_main(
    const float* __restrict__ x, const float* __restrict__ emb,
    float* __restrict__ out_idx, float* __restrict__ out_q,
    double* __restrict__ ws) {
  __shared__ Lds L;
  const int tid = threadIdx.x;
  const int row0 = blockIdx.x * ROWS_PER_BLOCK;

  // ---- stage codebook into LDS (padded rows), coalesced ----
  const float4* emb4 = (const float4*)emb;
  #pragma unroll
  for (int i = 0; i < 16; ++i) {
    int f = tid + i * BLOCK;           // 0..8191 float4
    int k = f >> 4, c = f & 15;
    L.cb[k * CBS + c] = emb4[f];
  }
  // ---- s2_k from global (L2-hot), one code row per thread ----
  {
    float4 er[16];
    const float4* p = emb4 + tid * 16;
    #pragma unroll
    for (int c = 0; c < 16; ++c) er[c] = p[c];
    L.bf[tid] = pairwise64_sq(er);
  }

  // ---- load my two rows into registers ----
  const int rA = row0 + tid;
  const int rB = rA + BLOCK;
  float4 xv[16], yv[16];
  {
    const float4* pa = (const float4*)(x + (size_t)rA * DIMS);
    const float4* pb = (const float4*)(x + (size_t)rB * DIMS);
    #pragma unroll
    for (int c = 0; c < 16; ++c) { xv[c] = pa[c]; yv[c] = pb[c]; }
  }
  const float s1A = pairwise64_sq(xv);
  const float s1B = pairwise64_sq(yv);

  __syncthreads();

  // ---- f32 scan over all codes, replicating reference rounding ----
  float d1A = 3.4e38f, d1B = 3.4e38f;
  int kA = 0, kB = 0;
  #pragma unroll 2
  for (int k = 0; k < KCODES; ++k) {
    const float4* e = &L.cb[k * CBS];
    float accA = 0.f, accB = 0.f;     // SERIAL ascending-j FMA chains
    #pragma unroll
    for (int c = 0; c < 16; ++c) {
      float4 ev = e[c];
      float4 xc = xv[c];
      float4 yc = yv[c];
      accA = fmaf(xc.x, ev.x, accA);
      accA = fmaf(xc.y, ev.y, accA);
      accA = fmaf(xc.z, ev.z, accA);
      accA = fmaf(xc.w, ev.w, accA);
      accB = fmaf(yc.x, ev.x, accB);
      accB = fmaf(yc.y, ev.y, accB);
      accB = fmaf(yc.z, ev.z, accB);
      accB = fmaf(yc.w, ev.w, accB);
    }
    float bk = L.bf[k];
    float SA = s1A + bk;              // fl32(s1 + s2_k)
    float SB = s1B + bk;
    float dA = SA - 2.0f * accA;      // fl32(S - 2m)  (2*acc exact)
    float dB = SB - 2.0f * accB;
    if (dA < d1A) { d1A = dA; kA = k; }   // strict < : first index wins ties
    if (dB < d1B) { d1B = dB; kB = k; }
  }

  // ---- per-row loss terms (read e_best from LDS) ----
  double lsum = 0.0;
  {
    const float4* ea = &L.cb[kA * CBS];
    const float4* eb = &L.cb[kB * CBS];
    #pragma unroll
    for (int c = 0; c < 16; ++c) {
      float4 va = ea[c], vb = eb[c];
      float4 xc = xv[c], yc = yv[c];
      float a0 = va.x - xc.x, a1 = va.y - xc.y, a2 = va.z - xc.z, a3 = va.w - xc.w;
      float c0 = vb.x - yc.x, c1 = vb.y - yc.y, c2 = vb.z - yc.z, c3 = vb.w - yc.w;
      lsum += (double)a0 * a0 + (double)a1 * a1 + (double)a2 * a2 + (double)a3 * a3;
      lsum += (double)c0 * c0 + (double)c1 * c1 + (double)c2 * c2 + (double)c3 * c3;
    }
  }

  out_idx[rA] = (float)kA;
  out_idx[rB] = (float)kB;
  L.kidx[tid] = kA;
  L.kidx[tid + BLOCK] = kB;

  // wave-level loss reduce, then stash per-wave partials
  #pragma unroll
  for (int off = 32; off > 0; off >>= 1) lsum += __shfl_down(lsum, off);
  if ((tid & 63) == 0) L.red[tid >> 6] = lsum;

  __syncthreads();

  if (tid == 0) {
    double s = 0.0;
    #pragma unroll
    for (int w = 0; w < 8; ++w) s += L.red[w];
    ws[blockIdx.x] = s;   // written every launch -> no init needed
  }

  // ---- coalesced quantized write: gather codebook rows via LDS kidx ----
  float4* outq4 = (float4*)out_q;
  #pragma unroll
  for (int it = 0; it < 32; ++it) {
    int idx = it * BLOCK + tid;        // 0..16383
    int r = idx >> 4, c = idx & 15;
    float4 v = L.cb[L.kidx[r] * CBS + c];
    outq4[(size_t)(row0 + r) * 16 + c] = v;
  }
}

__global__ void vq_loss_finalize(const double* __restrict__ ws,
                                 float* __restrict__ out_loss) {
  double s = 0.0;
  for (int i = threadIdx.x; i < GRID; i += 64) s += ws[i];
  #pragma unroll
  for (int off = 32; off > 0; off >>= 1) s += __shfl_down(s, off);
  if (threadIdx.x == 0)
    *out_loss = (float)(1.25 * s / (double)((size_t)NROWS * DIMS));
}

extern "C" void kernel_launch(void* const* d_in, const int* in_sizes, int n_in,
                              void* d_out, int out_size, void* d_ws, size_t ws_size,
                              hipStream_t stream) {
  (void)in_sizes; (void)n_in; (void)out_size; (void)ws_size;
  const float* x   = (const float*)d_in[0];
  const float* emb = (const float*)d_in[1];
  float* out      = (float*)d_out;
  float* out_idx  = out;                       // NROWS entries
  float* out_q    = out + NROWS;               // NROWS*DIMS entries
  float* out_loss = out + NROWS + (size_t)NROWS * DIMS;  // 1 entry
  double* ws = (double*)d_ws;                  // GRID doubles of scratch

  vq_main<<<GRID, BLOCK, 0, stream>>>(x, emb, out_idx, out_q, ws);
  vq_loss_finalize<<<1, 64, 0, stream>>>(ws, out_loss);
}